// Round 6
// baseline (175.530 us; speedup 1.0000x reference)
//
#include <hip/hip_runtime.h>
#include <stdint.h>

// instant-NGP hash encode (L=4, F=2, T=19, res {2,5,12,32}) + MLP 8->16->16->2
// One point per thread. Weights staged in LDS (wave-uniform broadcast reads).

#define TBL_ENTRIES (1u << 19)
#define HASH_MASK   (TBL_ENTRIES - 1u)
#define NPTS        2097152

__global__ __launch_bounds__(256) void ngp_fused(
    const float* __restrict__ x,      // [N,3]
    const float* __restrict__ table,  // [4, 2^19, 2]
    const float* __restrict__ W0,     // [16,8]
    const float* __restrict__ b0,     // [16]
    const float* __restrict__ W1,     // [16,16]
    const float* __restrict__ b1,     // [16]
    const float* __restrict__ W2,     // [2,16]
    const float* __restrict__ b2,     // [2]
    const int*   __restrict__ group,  // [1]
    float* __restrict__ out,          // [N,2]
    int n)
{
    // ---- stage weights into LDS: [0,128)=W0 [128,144)=b0 [144,400)=W1
    //      [400,416)=b1 [416,448)=W2 [448,450)=b2
    __shared__ float sw[452];
    const int t = threadIdx.x;
    for (int i = t; i < 450; i += 256) {
        float v;
        if      (i < 128) v = W0[i];
        else if (i < 144) v = b0[i - 128];
        else if (i < 400) v = W1[i - 144];
        else if (i < 416) v = b1[i - 400];
        else if (i < 448) v = W2[i - 416];
        else              v = b2[i - 448];
        sw[i] = v;
    }
    __syncthreads();

    const int gid = blockIdx.x * 256 + t;
    if (gid >= n) return;

    const int grp = *group;  // wave-uniform

    // ---- load point, preprocess to [0,1)
    const float x0 = x[3 * gid + 0];
    const float x1 = x[3 * gid + 1];
    const float x2 = x[3 * gid + 2];
    const float p0 = (x0 + 1.0f) * 0.5f;
    const float p1 = (x1 + 1.0f) * 0.5f;
    const float p2 = (x2 + 1.0f) * 0.5f;

    // ---- hash encoding, 4 levels -> feat[8]
    float feat[8];
    const float RESF[4] = {2.0f, 5.0f, 12.0f, 32.0f};
    const float2* __restrict__ tbl2 = reinterpret_cast<const float2*>(table);

    #pragma unroll
    for (int l = 0; l < 4; ++l) {
        const float res = RESF[l];
        const float sx = p0 * res, sy = p1 * res, sz = p2 * res;
        const float fx = floorf(sx), fy = floorf(sy), fz = floorf(sz);
        const float wx = sx - fx, wy = sy - fy, wz = sz - fz;
        const uint32_t ix = (uint32_t)(int)fx;
        const uint32_t iy = (uint32_t)(int)fy;
        const uint32_t iz = (uint32_t)(int)fz;
        // per-dim hashed coords for corner bit 0/1 (prime for dim0 is 1)
        const uint32_t hx0 = ix,                     hx1 = ix + 1u;
        const uint32_t hy0 = iy * 2654435761u,       hy1 = (iy + 1u) * 2654435761u;
        const uint32_t hz0 = iz * 805459861u,        hz1 = (iz + 1u) * 805459861u;
        const float ux = 1.0f - wx, uy = 1.0f - wy, uz = 1.0f - wz;
        const float2* __restrict__ tl = tbl2 + (size_t)l * TBL_ENTRIES;

        float f0 = 0.0f, f1 = 0.0f;
        #pragma unroll
        for (int c = 0; c < 8; ++c) {
            const uint32_t hx = (c & 1) ? hx1 : hx0;
            const uint32_t hy = (c & 2) ? hy1 : hy0;
            const uint32_t hz = (c & 4) ? hz1 : hz0;
            const uint32_t idx = (hx ^ hy ^ hz) & HASH_MASK;
            const float wc = ((c & 1) ? wx : ux) *
                             ((c & 2) ? wy : uy) *
                             ((c & 4) ? wz : uz);
            const float2 tv = tl[idx];
            f0 += wc * tv.x;
            f1 += wc * tv.y;
        }
        feat[2 * l + 0] = f0;
        feat[2 * l + 1] = f1;
    }

    // ---- MLP (fp32, LDS broadcast weight reads)
    const float4* sW0 = reinterpret_cast<const float4*>(sw);         // 32 x float4
    const float4* sW1 = reinterpret_cast<const float4*>(sw + 144);   // 64 x float4
    const float4* sW2 = reinterpret_cast<const float4*>(sw + 416);   // 8 x float4

    float h0[16];
    #pragma unroll
    for (int o = 0; o < 16; ++o) {
        const float4 a = sW0[2 * o];
        const float4 b = sW0[2 * o + 1];
        float acc = sw[128 + o];
        acc += a.x * feat[0] + a.y * feat[1] + a.z * feat[2] + a.w * feat[3];
        acc += b.x * feat[4] + b.y * feat[5] + b.z * feat[6] + b.w * feat[7];
        h0[o] = (grp == 1) ? fmaxf(acc, 0.0f) : acc;
    }

    float h1[16];
    #pragma unroll
    for (int o = 0; o < 16; ++o) {
        float acc = sw[400 + o];
        #pragma unroll
        for (int q = 0; q < 4; ++q) {
            const float4 a = sW1[4 * o + q];
            acc += a.x * h0[4 * q + 0] + a.y * h0[4 * q + 1] +
                   a.z * h0[4 * q + 2] + a.w * h0[4 * q + 3];
        }
        h1[o] = (grp == 1) ? fmaxf(acc, 0.0f) : acc;
    }

    float acc0 = sw[448];
    float acc1 = sw[449];
    #pragma unroll
    for (int q = 0; q < 4; ++q) {
        const float4 a0 = sW2[q];
        const float4 a1 = sW2[4 + q];
        acc0 += a0.x * h1[4 * q + 0] + a0.y * h1[4 * q + 1] +
                a0.z * h1[4 * q + 2] + a0.w * h1[4 * q + 3];
        acc1 += a1.x * h1[4 * q + 0] + a1.y * h1[4 * q + 1] +
                a1.z * h1[4 * q + 2] + a1.w * h1[4 * q + 3];
    }

    float2 o2;
    o2.x = acc0;
    o2.y = acc1;
    *reinterpret_cast<float2*>(out + 2 * gid) = o2;
}

extern "C" void kernel_launch(void* const* d_in, const int* in_sizes, int n_in,
                              void* d_out, int out_size, void* d_ws, size_t ws_size,
                              hipStream_t stream) {
    const float* x     = (const float*)d_in[0];
    const float* table = (const float*)d_in[1];
    const float* W0    = (const float*)d_in[2];
    const float* b0    = (const float*)d_in[3];
    const float* W1    = (const float*)d_in[4];
    const float* b1    = (const float*)d_in[5];
    const float* W2    = (const float*)d_in[6];
    const float* b2    = (const float*)d_in[7];
    const int*   group = (const int*)d_in[8];
    float* out = (float*)d_out;

    const int n = in_sizes[0] / 3;  // 2097152
    const int block = 256;
    const int grid = (n + block - 1) / block;
    ngp_fused<<<grid, block, 0, stream>>>(x, table, W0, b0, W1, b1, W2, b2,
                                          group, out, n);
}

// Round 8
// 172.618 us; speedup vs baseline: 1.0169x; 1.0169x over previous
//
#include <hip/hip_runtime.h>
#include <stdint.h>

// instant-NGP hash encode (L=4, F=2, T=19, res {2,5,12,32}) + MLP 8->16->16->2
// One point per thread. All 32 gathers issued as one batch (32-bit byte
// offsets -> saddr-form global loads). Weights read via scalar loads
// (uniform address, compile-time indices) -> no LDS at all.

#define TBL_ENTRIES (1u << 19)
#define HASH_MASK   (TBL_ENTRIES - 1u)

__global__ __launch_bounds__(256) void ngp_fused(
    const float* __restrict__ x,      // [N,3]
    const float* __restrict__ table,  // [4, 2^19, 2]
    const float* __restrict__ W0,     // [16,8]
    const float* __restrict__ b0,     // [16]
    const float* __restrict__ W1,     // [16,16]
    const float* __restrict__ b1,     // [16]
    const float* __restrict__ W2,     // [2,16]
    const float* __restrict__ b2,     // [2]
    const int*   __restrict__ group,  // [1]
    float* __restrict__ out,          // [N,2]
    int n)
{
    const int gid = blockIdx.x * 256 + threadIdx.x;
    if (gid >= n) return;

    const int grp = *group;  // uniform scalar load

    // ---- load point, preprocess to [0,1)
    const float x0 = x[3 * gid + 0];
    const float x1 = x[3 * gid + 1];
    const float x2 = x[3 * gid + 2];
    const float p0 = (x0 + 1.0f) * 0.5f;
    const float p1 = (x1 + 1.0f) * 0.5f;
    const float p2 = (x2 + 1.0f) * 0.5f;

    // ---- compute all 32 corner offsets (bytes) + trilinear weights
    const float RESF[4] = {2.0f, 5.0f, 12.0f, 32.0f};
    uint32_t off[32];
    float    wcs[32];

    #pragma unroll
    for (int l = 0; l < 4; ++l) {
        const float res = RESF[l];
        const float sx = p0 * res, sy = p1 * res, sz = p2 * res;
        const float fx = floorf(sx), fy = floorf(sy), fz = floorf(sz);
        const float wx = sx - fx, wy = sy - fy, wz = sz - fz;
        const uint32_t ix = (uint32_t)(int)fx;
        const uint32_t iy = (uint32_t)(int)fy;
        const uint32_t iz = (uint32_t)(int)fz;
        const uint32_t hx0 = ix,               hx1 = ix + 1u;
        const uint32_t hy0 = iy * 2654435761u, hy1 = (iy + 1u) * 2654435761u;
        const uint32_t hz0 = iz * 805459861u,  hz1 = (iz + 1u) * 805459861u;
        const float ux = 1.0f - wx, uy = 1.0f - wy, uz = 1.0f - wz;
        // (x*y) pre-products; final weight = (x*y)*z, same assoc as reference
        const float w00 = ux * uy, w10 = wx * uy, w01 = ux * wy, w11 = wx * wy;

        #pragma unroll
        for (int c = 0; c < 8; ++c) {
            const uint32_t hx = (c & 1) ? hx1 : hx0;
            const uint32_t hy = (c & 2) ? hy1 : hy0;
            const uint32_t hz = (c & 4) ? hz1 : hz0;
            const uint32_t idx = (hx ^ hy ^ hz) & HASH_MASK;
            // byte offset into [4, 2^19, 2] f32 table: l*4MB + idx*8B (fits u32)
            off[8 * l + c] = ((uint32_t)l << 22) | (idx << 3);
            const float wxy = (c & 2) ? ((c & 1) ? w11 : w01)
                                      : ((c & 1) ? w10 : w00);
            wcs[8 * l + c] = wxy * ((c & 4) ? wz : uz);
        }
    }

    // ---- issue all 32 gathers back-to-back (maximize outstanding loads)
    const char* tbase = (const char*)table;
    float2 tv[32];
    #pragma unroll
    for (int i = 0; i < 32; ++i)
        tv[i] = *(const float2*)(tbase + off[i]);

    // ---- weighted accumulation, corner order preserved
    float feat[8];
    #pragma unroll
    for (int l = 0; l < 4; ++l) {
        float f0 = 0.0f, f1 = 0.0f;
        #pragma unroll
        for (int c = 0; c < 8; ++c) {
            f0 += wcs[8 * l + c] * tv[8 * l + c].x;
            f1 += wcs[8 * l + c] * tv[8 * l + c].y;
        }
        feat[2 * l + 0] = f0;
        feat[2 * l + 1] = f1;
    }

    // ---- MLP (fp32). Weights read with constant indices from uniform
    //      kernarg pointers -> scalar loads through the scalar cache.
    const float4* __restrict__ gW0 = reinterpret_cast<const float4*>(W0); // 32
    const float4* __restrict__ gW1 = reinterpret_cast<const float4*>(W1); // 64
    const float4* __restrict__ gW2 = reinterpret_cast<const float4*>(W2); // 8

    float h0[16];
    #pragma unroll
    for (int o = 0; o < 16; ++o) {
        const float4 a = gW0[2 * o];
        const float4 b = gW0[2 * o + 1];
        float acc = b0[o];
        acc += a.x * feat[0] + a.y * feat[1] + a.z * feat[2] + a.w * feat[3];
        acc += b.x * feat[4] + b.y * feat[5] + b.z * feat[6] + b.w * feat[7];
        h0[o] = (grp == 1) ? fmaxf(acc, 0.0f) : acc;
    }

    float h1[16];
    #pragma unroll
    for (int o = 0; o < 16; ++o) {
        float acc = b1[o];
        #pragma unroll
        for (int q = 0; q < 4; ++q) {
            const float4 a = gW1[4 * o + q];
            acc += a.x * h0[4 * q + 0] + a.y * h0[4 * q + 1] +
                   a.z * h0[4 * q + 2] + a.w * h0[4 * q + 3];
        }
        h1[o] = (grp == 1) ? fmaxf(acc, 0.0f) : acc;
    }

    float acc0 = b2[0];
    float acc1 = b2[1];
    #pragma unroll
    for (int q = 0; q < 4; ++q) {
        const float4 a0 = gW2[q];
        const float4 a1 = gW2[4 + q];
        acc0 += a0.x * h1[4 * q + 0] + a0.y * h1[4 * q + 1] +
                a0.z * h1[4 * q + 2] + a0.w * h1[4 * q + 3];
        acc1 += a1.x * h1[4 * q + 0] + a1.y * h1[4 * q + 1] +
                a1.z * h1[4 * q + 2] + a1.w * h1[4 * q + 3];
    }

    float2 o2;
    o2.x = acc0;
    o2.y = acc1;
    *reinterpret_cast<float2*>(out + 2 * gid) = o2;
}

extern "C" void kernel_launch(void* const* d_in, const int* in_sizes, int n_in,
                              void* d_out, int out_size, void* d_ws, size_t ws_size,
                              hipStream_t stream) {
    const float* x     = (const float*)d_in[0];
    const float* table = (const float*)d_in[1];
    const float* W0    = (const float*)d_in[2];
    const float* b0    = (const float*)d_in[3];
    const float* W1    = (const float*)d_in[4];
    const float* b1    = (const float*)d_in[5];
    const float* W2    = (const float*)d_in[6];
    const float* b2    = (const float*)d_in[7];
    const int*   group = (const int*)d_in[8];
    float* out = (float*)d_out;

    const int n = in_sizes[0] / 3;  // 2097152
    const int block = 256;
    const int grid = (n + block - 1) / block;
    ngp_fused<<<grid, block, 0, stream>>>(x, table, W0, b0, W1, b1, W2, b2,
                                          group, out, n);
}

// Round 10
// 141.206 us; speedup vs baseline: 1.2431x; 1.2225x over previous
//
#include <hip/hip_runtime.h>
#include <stdint.h>

// instant-NGP hash encode (L=4, F=2, T=19, res {2,5,12,32}) + MLP 8->16->16->2
// Key structure: levels 0-2 touch only 27+216+2197=2440 distinct table entries
// GLOBALLY. A dehash kernel densifies them into d_ws; the main kernel stages
// that 19.5KB into LDS (coalesced) and interpolates levels 0-2 from LDS with
// direct 3D indexing (no hash). Only level 3 (res 32) gathers from global.

#define TBL_ENTRIES (1u << 19)
#define HASH_MASK   (TBL_ENTRIES - 1u)

#define D0 3
#define D1 6
#define D2 13
#define N0 (D0*D0*D0)            // 27
#define N1 (D1*D1*D1)            // 216
#define N2 (D2*D2*D2)            // 2197
#define NDENSE (N0 + N1 + N2)    // 2440 float2 = 19520 B

__global__ __launch_bounds__(256) void dehash_kernel(
    const float* __restrict__ table, float2* __restrict__ dense)
{
    const int i = blockIdx.x * 256 + threadIdx.x;
    if (i >= NDENSE) return;
    int l, e, D;
    if (i < N0)           { l = 0; e = i;           D = D0; }
    else if (i < N0 + N1) { l = 1; e = i - N0;      D = D1; }
    else                  { l = 2; e = i - N0 - N1; D = D2; }
    const int a = e / (D * D);
    const int r = e - a * D * D;
    const int b = r / D;
    const int c = r - b * D;
    const uint32_t h = ((uint32_t)a)
                     ^ (((uint32_t)b) * 2654435761u)
                     ^ (((uint32_t)c) * 805459861u);
    const float2* t2 = reinterpret_cast<const float2*>(table);
    dense[i] = t2[(size_t)l * TBL_ENTRIES + (h & HASH_MASK)];
}

__global__ __launch_bounds__(256) void ngp_fused(
    const float* __restrict__ x,      // [N,3]
    const float* __restrict__ table,  // [4, 2^19, 2]
    const float2* __restrict__ dense, // [2440] densified L0-2
    const float* __restrict__ W0,     // [16,8]
    const float* __restrict__ b0,     // [16]
    const float* __restrict__ W1,     // [16,16]
    const float* __restrict__ b1,     // [16]
    const float* __restrict__ W2,     // [2,16]
    const float* __restrict__ b2,     // [2]
    const int*   __restrict__ group,  // [1]
    float* __restrict__ out,          // [N,2]
    int n)
{
    __shared__ float2 sd[NDENSE];
    const int t = threadIdx.x;
    {   // coalesced stage: 2440 float2 = 1220 float4
        const float4* src4 = reinterpret_cast<const float4*>(dense);
        float4* dst4 = reinterpret_cast<float4*>(sd);
        #pragma unroll
        for (int i = 0; i < 5; ++i) {
            const int j = t + 256 * i;
            if (j < 1220) dst4[j] = src4[j];
        }
    }
    __syncthreads();

    const int gid = blockIdx.x * 256 + t;
    if (gid >= n) return;

    const int grp = *group;

    const float p0 = (x[3 * gid + 0] + 1.0f) * 0.5f;
    const float p1 = (x[3 * gid + 1] + 1.0f) * 0.5f;
    const float p2 = (x[3 * gid + 2] + 1.0f) * 0.5f;

    // ================= level 3 (res 32): hash + global gather, issue FIRST
    float wcs3[8];
    float2 tv[8];
    {
        const float sx = p0 * 32.0f, sy = p1 * 32.0f, sz = p2 * 32.0f;
        const float fx = floorf(sx), fy = floorf(sy), fz = floorf(sz);
        const float wx = sx - fx, wy = sy - fy, wz = sz - fz;
        const uint32_t ix = (uint32_t)(int)fx;
        const uint32_t iy = (uint32_t)(int)fy;
        const uint32_t iz = (uint32_t)(int)fz;
        const uint32_t hx0 = ix,               hx1 = ix + 1u;
        const uint32_t hy0 = iy * 2654435761u, hy1 = (iy + 1u) * 2654435761u;
        const uint32_t hz0 = iz * 805459861u,  hz1 = (iz + 1u) * 805459861u;
        const float ux = 1.0f - wx, uy = 1.0f - wy, uz = 1.0f - wz;
        const float w00 = ux * uy, w10 = wx * uy, w01 = ux * wy, w11 = wx * wy;
        const char* tbase = (const char*)table;
        uint32_t off[8];
        #pragma unroll
        for (int c = 0; c < 8; ++c) {
            const uint32_t hx = (c & 1) ? hx1 : hx0;
            const uint32_t hy = (c & 2) ? hy1 : hy0;
            const uint32_t hz = (c & 4) ? hz1 : hz0;
            const uint32_t idx = (hx ^ hy ^ hz) & HASH_MASK;
            off[c] = (3u << 22) | (idx << 3);    // byte offset into level 3
            const float wxy = (c & 2) ? ((c & 1) ? w11 : w01)
                                      : ((c & 1) ? w10 : w00);
            wcs3[c] = wxy * ((c & 4) ? wz : uz);
        }
        #pragma unroll
        for (int c = 0; c < 8; ++c)
            tv[c] = *(const float2*)(tbase + off[c]);
    }

    // ================= levels 0-2 from LDS (direct 3D index, no hash)
    float feat[8];
    const float RESF[3] = {2.0f, 5.0f, 12.0f};
    const int   DIMS[3] = {D0, D1, D2};
    const int   BASE[3] = {0, N0, N0 + N1};
    #pragma unroll
    for (int l = 0; l < 3; ++l) {
        const float res = RESF[l];
        const int   D   = DIMS[l];
        const float sx = p0 * res, sy = p1 * res, sz = p2 * res;
        const float fx = floorf(sx), fy = floorf(sy), fz = floorf(sz);
        const float wx = sx - fx, wy = sy - fy, wz = sz - fz;
        const int ix = (int)fx, iy = (int)fy, iz = (int)fz;
        const int base = BASE[l] + (ix * D + iy) * D + iz;
        const float ux = 1.0f - wx, uy = 1.0f - wy, uz = 1.0f - wz;
        const float w00 = ux * uy, w10 = wx * uy, w01 = ux * wy, w11 = wx * wy;
        float f0 = 0.0f, f1 = 0.0f;
        #pragma unroll
        for (int c = 0; c < 8; ++c) {
            const int o = base + ((c & 1) ? D * D : 0)
                               + ((c & 2) ? D : 0)
                               + ((c & 4) ? 1 : 0);
            const float wxy = (c & 2) ? ((c & 1) ? w11 : w01)
                                      : ((c & 1) ? w10 : w00);
            const float wc = wxy * ((c & 4) ? wz : uz);
            const float2 v = sd[o];
            f0 += wc * v.x;
            f1 += wc * v.y;
        }
        feat[2 * l + 0] = f0;
        feat[2 * l + 1] = f1;
    }

    // ================= combine level-3 gathers (loads were in flight)
    {
        float f0 = 0.0f, f1 = 0.0f;
        #pragma unroll
        for (int c = 0; c < 8; ++c) {
            f0 += wcs3[c] * tv[c].x;
            f1 += wcs3[c] * tv[c].y;
        }
        feat[6] = f0;
        feat[7] = f1;
    }

    // ================= MLP (fp32, scalar-cache weight reads)
    const float4* __restrict__ gW0 = reinterpret_cast<const float4*>(W0); // 32
    const float4* __restrict__ gW1 = reinterpret_cast<const float4*>(W1); // 64
    const float4* __restrict__ gW2 = reinterpret_cast<const float4*>(W2); // 8

    float h0[16];
    #pragma unroll
    for (int o = 0; o < 16; ++o) {
        const float4 a = gW0[2 * o];
        const float4 b = gW0[2 * o + 1];
        float acc = b0[o];
        acc += a.x * feat[0] + a.y * feat[1] + a.z * feat[2] + a.w * feat[3];
        acc += b.x * feat[4] + b.y * feat[5] + b.z * feat[6] + b.w * feat[7];
        h0[o] = (grp == 1) ? fmaxf(acc, 0.0f) : acc;
    }

    float h1[16];
    #pragma unroll
    for (int o = 0; o < 16; ++o) {
        float acc = b1[o];
        #pragma unroll
        for (int q = 0; q < 4; ++q) {
            const float4 a = gW1[4 * o + q];
            acc += a.x * h0[4 * q + 0] + a.y * h0[4 * q + 1] +
                   a.z * h0[4 * q + 2] + a.w * h0[4 * q + 3];
        }
        h1[o] = (grp == 1) ? fmaxf(acc, 0.0f) : acc;
    }

    float acc0 = b2[0];
    float acc1 = b2[1];
    #pragma unroll
    for (int q = 0; q < 4; ++q) {
        const float4 a0 = gW2[q];
        const float4 a1 = gW2[4 + q];
        acc0 += a0.x * h1[4 * q + 0] + a0.y * h1[4 * q + 1] +
                a0.z * h1[4 * q + 2] + a0.w * h1[4 * q + 3];
        acc1 += a1.x * h1[4 * q + 0] + a1.y * h1[4 * q + 1] +
                a1.z * h1[4 * q + 2] + a1.w * h1[4 * q + 3];
    }

    float2 o2;
    o2.x = acc0;
    o2.y = acc1;
    *reinterpret_cast<float2*>(out + 2 * gid) = o2;
}

extern "C" void kernel_launch(void* const* d_in, const int* in_sizes, int n_in,
                              void* d_out, int out_size, void* d_ws, size_t ws_size,
                              hipStream_t stream) {
    const float* x     = (const float*)d_in[0];
    const float* table = (const float*)d_in[1];
    const float* W0    = (const float*)d_in[2];
    const float* b0    = (const float*)d_in[3];
    const float* W1    = (const float*)d_in[4];
    const float* b1    = (const float*)d_in[5];
    const float* W2    = (const float*)d_in[6];
    const float* b2    = (const float*)d_in[7];
    const int*   group = (const int*)d_in[8];
    float* out = (float*)d_out;
    float2* dense = (float2*)d_ws;   // 2440 float2 = 19.5 KB scratch

    const int n = in_sizes[0] / 3;   // 2097152
    dehash_kernel<<<(NDENSE + 255) / 256, 256, 0, stream>>>(table, dense);
    const int block = 256;
    const int grid = (n + block - 1) / block;
    ngp_fused<<<grid, block, 0, stream>>>(x, table, dense, W0, b0, W1, b1,
                                          W2, b2, group, out, n);
}

// Round 11
// 139.741 us; speedup vs baseline: 1.2561x; 1.0105x over previous
//
#include <hip/hip_runtime.h>
#include <stdint.h>

// instant-NGP hash encode (L=4, F=2, T=19, res {2,5,12,32}) + MLP 8->16->16->2
// Levels 0-2 touch only 2440 distinct entries globally -> densified into d_ws,
// staged to LDS, direct 3D indexing (no hash). Level 3 touches only 33^3=35937
// entries (287KB) -> densified into d_ws as [33][33][33] z-fastest; its 8
// corners become 4 contiguous 16B loads (z,z+1 pairs) with tight locality.

#define TBL_ENTRIES (1u << 19)
#define HASH_MASK   (TBL_ENTRIES - 1u)

#define D0 3
#define D1 6
#define D2 13
#define D3 33
#define N0 (D0*D0*D0)            // 27
#define N1 (D1*D1*D1)            // 216
#define N2 (D2*D2*D2)            // 2197
#define N3 (D3*D3*D3)            // 35937
#define NDENSE (N0 + N1 + N2)    // 2440 float2 = 19520 B (LDS)
#define NTOTAL (NDENSE + N3)     // 38377 float2 = 307 KB (d_ws)

__global__ __launch_bounds__(256) void dehash_kernel(
    const float* __restrict__ table, float2* __restrict__ dense)
{
    const int i = blockIdx.x * 256 + threadIdx.x;
    if (i >= NTOTAL) return;
    int l, e, D;
    if (i < N0)                { l = 0; e = i;                D = D0; }
    else if (i < N0 + N1)      { l = 1; e = i - N0;           D = D1; }
    else if (i < NDENSE)       { l = 2; e = i - N0 - N1;      D = D2; }
    else                       { l = 3; e = i - NDENSE;       D = D3; }
    const int a = e / (D * D);           // x coord (prime 1)
    const int r = e - a * D * D;
    const int b = r / D;                 // y coord (prime 2654435761)
    const int c = r - b * D;             // z coord (prime 805459861)
    const uint32_t h = ((uint32_t)a)
                     ^ (((uint32_t)b) * 2654435761u)
                     ^ (((uint32_t)c) * 805459861u);
    const float2* t2 = reinterpret_cast<const float2*>(table);
    dense[i] = t2[(size_t)l * TBL_ENTRIES + (h & HASH_MASK)];
}

__global__ __launch_bounds__(256) void ngp_fused(
    const float* __restrict__ x,       // [N,3]
    const float2* __restrict__ dense,  // [2440] L0-2 densified
    const float2* __restrict__ dense3, // [33][33][33] L3 densified
    const float* __restrict__ W0,      // [16,8]
    const float* __restrict__ b0,      // [16]
    const float* __restrict__ W1,      // [16,16]
    const float* __restrict__ b1,      // [16]
    const float* __restrict__ W2,      // [2,16]
    const float* __restrict__ b2,      // [2]
    const int*   __restrict__ group,   // [1]
    float* __restrict__ out,           // [N,2]
    int n)
{
    __shared__ float2 sd[NDENSE];
    const int t = threadIdx.x;
    {   // coalesced stage: 2440 float2 = 1220 float4
        const float4* src4 = reinterpret_cast<const float4*>(dense);
        float4* dst4 = reinterpret_cast<float4*>(sd);
        #pragma unroll
        for (int i = 0; i < 5; ++i) {
            const int j = t + 256 * i;
            if (j < 1220) dst4[j] = src4[j];
        }
    }
    __syncthreads();

    const int gid = blockIdx.x * 256 + t;
    if (gid >= n) return;

    const int grp = *group;

    const float p0 = (x[3 * gid + 0] + 1.0f) * 0.5f;
    const float p1 = (x[3 * gid + 1] + 1.0f) * 0.5f;
    const float p2 = (x[3 * gid + 2] + 1.0f) * 0.5f;

    // ===== level 3 (res 32): dense [33][33][33], issue 4x16B loads FIRST
    float wcs3[8];
    float2 tv[8];
    {
        const float sx = p0 * 32.0f, sy = p1 * 32.0f, sz = p2 * 32.0f;
        const float fx = floorf(sx), fy = floorf(sy), fz = floorf(sz);
        const float wx = sx - fx, wy = sy - fy, wz = sz - fz;
        const int ix = (int)fx, iy = (int)fy, iz = (int)fz;
        const float ux = 1.0f - wx, uy = 1.0f - wy, uz = 1.0f - wz;
        const float w00 = ux * uy, w10 = wx * uy, w01 = ux * wy, w11 = wx * wy;
        #pragma unroll
        for (int c = 0; c < 8; ++c) {
            const float wxy = (c & 2) ? ((c & 1) ? w11 : w01)
                                      : ((c & 1) ? w10 : w00);
            wcs3[c] = wxy * ((c & 4) ? wz : uz);
        }
        // rows: (x+dx, y+dy) -> two consecutive float2 (z, z+1) = 16B
        const float2* r00 = dense3 + (ix * D3 + iy) * D3 + iz;
        const float2* r10 = r00 + D3 * D3;
        const float2* r01 = r00 + D3;
        const float2* r11 = r10 + D3;
        const float2 v000 = r00[0], v001 = r00[1];
        const float2 v100 = r10[0], v101 = r10[1];
        const float2 v010 = r01[0], v011 = r01[1];
        const float2 v110 = r11[0], v111 = r11[1];
        // c bits: 1->x+1, 2->y+1, 4->z+1 ; keep ascending-c accumulation
        tv[0] = v000; tv[1] = v100; tv[2] = v010; tv[3] = v110;
        tv[4] = v001; tv[5] = v101; tv[6] = v011; tv[7] = v111;
    }

    // ===== levels 0-2 from LDS (direct 3D index, no hash)
    float feat[8];
    const float RESF[3] = {2.0f, 5.0f, 12.0f};
    const int   DIMS[3] = {D0, D1, D2};
    const int   BASE[3] = {0, N0, N0 + N1};
    #pragma unroll
    for (int l = 0; l < 3; ++l) {
        const float res = RESF[l];
        const int   D   = DIMS[l];
        const float sx = p0 * res, sy = p1 * res, sz = p2 * res;
        const float fx = floorf(sx), fy = floorf(sy), fz = floorf(sz);
        const float wx = sx - fx, wy = sy - fy, wz = sz - fz;
        const int ix = (int)fx, iy = (int)fy, iz = (int)fz;
        const int base = BASE[l] + (ix * D + iy) * D + iz;
        const float ux = 1.0f - wx, uy = 1.0f - wy, uz = 1.0f - wz;
        const float w00 = ux * uy, w10 = wx * uy, w01 = ux * wy, w11 = wx * wy;
        float f0 = 0.0f, f1 = 0.0f;
        #pragma unroll
        for (int c = 0; c < 8; ++c) {
            const int o = base + ((c & 1) ? D * D : 0)
                               + ((c & 2) ? D : 0)
                               + ((c & 4) ? 1 : 0);
            const float wxy = (c & 2) ? ((c & 1) ? w11 : w01)
                                      : ((c & 1) ? w10 : w00);
            const float wc = wxy * ((c & 4) ? wz : uz);
            const float2 v = sd[o];
            f0 += wc * v.x;
            f1 += wc * v.y;
        }
        feat[2 * l + 0] = f0;
        feat[2 * l + 1] = f1;
    }

    // ===== combine level-3 (loads were in flight during LDS work)
    {
        float f0 = 0.0f, f1 = 0.0f;
        #pragma unroll
        for (int c = 0; c < 8; ++c) {
            f0 += wcs3[c] * tv[c].x;
            f1 += wcs3[c] * tv[c].y;
        }
        feat[6] = f0;
        feat[7] = f1;
    }

    // ===== MLP (fp32, scalar-cache weight reads)
    const float4* __restrict__ gW0 = reinterpret_cast<const float4*>(W0); // 32
    const float4* __restrict__ gW1 = reinterpret_cast<const float4*>(W1); // 64
    const float4* __restrict__ gW2 = reinterpret_cast<const float4*>(W2); // 8

    float h0[16];
    #pragma unroll
    for (int o = 0; o < 16; ++o) {
        const float4 a = gW0[2 * o];
        const float4 b = gW0[2 * o + 1];
        float acc = b0[o];
        acc += a.x * feat[0] + a.y * feat[1] + a.z * feat[2] + a.w * feat[3];
        acc += b.x * feat[4] + b.y * feat[5] + b.z * feat[6] + b.w * feat[7];
        h0[o] = (grp == 1) ? fmaxf(acc, 0.0f) : acc;
    }

    float h1[16];
    #pragma unroll
    for (int o = 0; o < 16; ++o) {
        float acc = b1[o];
        #pragma unroll
        for (int q = 0; q < 4; ++q) {
            const float4 a = gW1[4 * o + q];
            acc += a.x * h0[4 * q + 0] + a.y * h0[4 * q + 1] +
                   a.z * h0[4 * q + 2] + a.w * h0[4 * q + 3];
        }
        h1[o] = (grp == 1) ? fmaxf(acc, 0.0f) : acc;
    }

    float acc0 = b2[0];
    float acc1 = b2[1];
    #pragma unroll
    for (int q = 0; q < 4; ++q) {
        const float4 a0 = gW2[q];
        const float4 a1 = gW2[4 + q];
        acc0 += a0.x * h1[4 * q + 0] + a0.y * h1[4 * q + 1] +
                a0.z * h1[4 * q + 2] + a0.w * h1[4 * q + 3];
        acc1 += a1.x * h1[4 * q + 0] + a1.y * h1[4 * q + 1] +
                a1.z * h1[4 * q + 2] + a1.w * h1[4 * q + 3];
    }

    float2 o2;
    o2.x = acc0;
    o2.y = acc1;
    *reinterpret_cast<float2*>(out + 2 * gid) = o2;
}

extern "C" void kernel_launch(void* const* d_in, const int* in_sizes, int n_in,
                              void* d_out, int out_size, void* d_ws, size_t ws_size,
                              hipStream_t stream) {
    const float* x     = (const float*)d_in[0];
    const float* table = (const float*)d_in[1];
    const float* W0    = (const float*)d_in[2];
    const float* b0    = (const float*)d_in[3];
    const float* W1    = (const float*)d_in[4];
    const float* b1    = (const float*)d_in[5];
    const float* W2    = (const float*)d_in[6];
    const float* b2    = (const float*)d_in[7];
    const int*   group = (const int*)d_in[8];
    float* out = (float*)d_out;
    float2* dense  = (float2*)d_ws;          // [2440]  L0-2
    float2* dense3 = dense + NDENSE;         // [35937] L3   (total 307 KB)

    const int n = in_sizes[0] / 3;   // 2097152
    dehash_kernel<<<(NTOTAL + 255) / 256, 256, 0, stream>>>(table, dense);
    const int block = 256;
    const int grid = (n + block - 1) / block;
    ngp_fused<<<grid, block, 0, stream>>>(x, dense, dense3, W0, b0, W1, b1,
                                          W2, b2, group, out, n);
}

// Round 14
// 134.425 us; speedup vs baseline: 1.3058x; 1.0395x over previous
//
#include <hip/hip_runtime.h>
#include <stdint.h>

// instant-NGP hash encode (L=4, F=2, T=19, res {2,5,12,32}) + MLP 8->16->16->2
// L0-2 densified (2440 entries) -> LDS direct-index. L3 densified 33^3 dense
// grid in d_ws. NEW this round: packed fp32 (v_pk_fma_f32) for interpolation
// accumulate + whole MLP; weights pre-transposed into d_ws by dehash kernel
// so output-pair weight loads are contiguous scalar dwordx2.

#define TBL_ENTRIES (1u << 19)
#define HASH_MASK   (TBL_ENTRIES - 1u)

#define D0 3
#define D1 6
#define D2 13
#define D3 33
#define N0 (D0*D0*D0)            // 27
#define N1 (D1*D1*D1)            // 216
#define N2 (D2*D2*D2)            // 2197
#define N3 (D3*D3*D3)            // 35937
#define NDENSE (N0 + N1 + N2)    // 2440 float2 (LDS)
#define NTOTAL (NDENSE + N3)     // 38377 float2 in d_ws
#define NWT    416               // 128 + 256 + 32 transposed weight floats

typedef float v2f __attribute__((ext_vector_type(2)));
#define FMA2(a,b,c) __builtin_elementwise_fma((a),(b),(c))

__global__ __launch_bounds__(256) void dehash_kernel(
    const float* __restrict__ table,
    const float* __restrict__ W0,   // [16,8]
    const float* __restrict__ W1,   // [16,16]
    const float* __restrict__ W2,   // [2,16]
    float2* __restrict__ dense)     // [NTOTAL] + wt[NWT] floats after
{
    const int i = blockIdx.x * 256 + threadIdx.x;
    if (i < NTOTAL) {
        int l, e, D;
        if (i < N0)           { l = 0; e = i;           D = D0; }
        else if (i < N0 + N1) { l = 1; e = i - N0;      D = D1; }
        else if (i < NDENSE)  { l = 2; e = i - N0 - N1; D = D2; }
        else                  { l = 3; e = i - NDENSE;  D = D3; }
        const int a = e / (D * D);
        const int r = e - a * D * D;
        const int b = r / D;
        const int c = r - b * D;
        const uint32_t h = ((uint32_t)a)
                         ^ (((uint32_t)b) * 2654435761u)
                         ^ (((uint32_t)c) * 805459861u);
        const float2* t2 = reinterpret_cast<const float2*>(table);
        dense[i] = t2[(size_t)l * TBL_ENTRIES + (h & HASH_MASK)];
    } else if (i < NTOTAL + NWT) {
        // transposed weights: wt0[i8][o16]=W0[o][i8]; wt1[i16][o16]=W1[o][i];
        // wt2[i16][o2]=W2[o][i]
        float* wt = reinterpret_cast<float*>(dense + NTOTAL);
        const int j = i - NTOTAL;
        float v;
        if (j < 128)      { const int ii = j >> 4, o = j & 15; v = W0[o * 8 + ii]; }
        else if (j < 384) { const int k = j - 128; const int ii = k >> 4, o = k & 15; v = W1[o * 16 + ii]; }
        else              { const int m = j - 384; const int ii = m >> 1, o = m & 1;  v = W2[o * 16 + ii]; }
        wt[j] = v;
    }
}

__global__ __launch_bounds__(256) void ngp_fused(
    const float* __restrict__ x,       // [N,3]
    const float2* __restrict__ dense,  // [2440] L0-2
    const float2* __restrict__ dense3, // [33][33][33] L3
    const v2f* __restrict__ wt0,       // [8][8]  pairs: {W0[2o][i],W0[2o+1][i]}
    const v2f* __restrict__ wt1,       // [16][8]
    const v2f* __restrict__ wt2,       // [16][1]
    const float* __restrict__ b0,      // [16]
    const float* __restrict__ b1,      // [16]
    const float* __restrict__ b2,      // [2]
    const int*   __restrict__ group,   // [1]
    float* __restrict__ out,           // [N,2]
    int n)
{
    __shared__ float2 sd[NDENSE];
    const int t = threadIdx.x;
    {   // coalesced stage: 2440 float2 = 1220 float4
        const float4* src4 = reinterpret_cast<const float4*>(dense);
        float4* dst4 = reinterpret_cast<float4*>(sd);
        #pragma unroll
        for (int i = 0; i < 5; ++i) {
            const int j = t + 256 * i;
            if (j < 1220) dst4[j] = src4[j];
        }
    }
    __syncthreads();

    const int gid = blockIdx.x * 256 + t;
    if (gid >= n) return;

    const int grp = *group;

    const float p0 = (x[3 * gid + 0] + 1.0f) * 0.5f;
    const float p1 = (x[3 * gid + 1] + 1.0f) * 0.5f;
    const float p2 = (x[3 * gid + 2] + 1.0f) * 0.5f;

    // ===== level 3 (res 32): dense [33][33][33], 4x16B loads issued FIRST
    float wcs3[8];
    v2f tv[8];
    {
        const float sx = p0 * 32.0f, sy = p1 * 32.0f, sz = p2 * 32.0f;
        const float fx = floorf(sx), fy = floorf(sy), fz = floorf(sz);
        const float wx = sx - fx, wy = sy - fy, wz = sz - fz;
        const int ix = (int)fx, iy = (int)fy, iz = (int)fz;
        const float ux = 1.0f - wx, uy = 1.0f - wy, uz = 1.0f - wz;
        const float w00 = ux * uy, w10 = wx * uy, w01 = ux * wy, w11 = wx * wy;
        #pragma unroll
        for (int c = 0; c < 8; ++c) {
            const float wxy = (c & 2) ? ((c & 1) ? w11 : w01)
                                      : ((c & 1) ? w10 : w00);
            wcs3[c] = wxy * ((c & 4) ? wz : uz);
        }
        const float2* r00 = dense3 + (ix * D3 + iy) * D3 + iz;
        const float2* r10 = r00 + D3 * D3;
        const float2* r01 = r00 + D3;
        const float2* r11 = r10 + D3;
        const v2f v000 = *(const v2f*)&r00[0], v001 = *(const v2f*)&r00[1];
        const v2f v100 = *(const v2f*)&r10[0], v101 = *(const v2f*)&r10[1];
        const v2f v010 = *(const v2f*)&r01[0], v011 = *(const v2f*)&r01[1];
        const v2f v110 = *(const v2f*)&r11[0], v111 = *(const v2f*)&r11[1];
        tv[0] = v000; tv[1] = v100; tv[2] = v010; tv[3] = v110;
        tv[4] = v001; tv[5] = v101; tv[6] = v011; tv[7] = v111;
    }

    // ===== levels 0-2 from LDS (direct 3D index, packed accumulate)
    float feat[8];
    const float RESF[3] = {2.0f, 5.0f, 12.0f};
    const int   DIMS[3] = {D0, D1, D2};
    const int   BASE[3] = {0, N0, N0 + N1};
    #pragma unroll
    for (int l = 0; l < 3; ++l) {
        const float res = RESF[l];
        const int   D   = DIMS[l];
        const float sx = p0 * res, sy = p1 * res, sz = p2 * res;
        const float fx = floorf(sx), fy = floorf(sy), fz = floorf(sz);
        const float wx = sx - fx, wy = sy - fy, wz = sz - fz;
        const int ix = (int)fx, iy = (int)fy, iz = (int)fz;
        const int base = BASE[l] + (ix * D + iy) * D + iz;
        const float ux = 1.0f - wx, uy = 1.0f - wy, uz = 1.0f - wz;
        const float w00 = ux * uy, w10 = wx * uy, w01 = ux * wy, w11 = wx * wy;
        v2f acc = {0.0f, 0.0f};
        #pragma unroll
        for (int c = 0; c < 8; ++c) {
            const int o = base + ((c & 1) ? D * D : 0)
                               + ((c & 2) ? D : 0)
                               + ((c & 4) ? 1 : 0);
            const float wxy = (c & 2) ? ((c & 1) ? w11 : w01)
                                      : ((c & 1) ? w10 : w00);
            const float wc = wxy * ((c & 4) ? wz : uz);
            const v2f v = *(const v2f*)&sd[o];
            const v2f wb = {wc, wc};
            acc = FMA2(wb, v, acc);
        }
        feat[2 * l + 0] = acc[0];
        feat[2 * l + 1] = acc[1];
    }

    // ===== combine level-3 (loads in flight during LDS work)
    {
        v2f acc = {0.0f, 0.0f};
        #pragma unroll
        for (int c = 0; c < 8; ++c) {
            const v2f wb = {wcs3[c], wcs3[c]};
            acc = FMA2(wb, tv[c], acc);
        }
        feat[6] = acc[0];
        feat[7] = acc[1];
    }

    // ===== MLP, fully packed: output pairs, pk_fma chains
    const v2f* b0p = reinterpret_cast<const v2f*>(b0);   // [8]
    const v2f* b1p = reinterpret_cast<const v2f*>(b1);   // [8]
    const v2f* b2p = reinterpret_cast<const v2f*>(b2);   // [1]
    const v2f zero = {0.0f, 0.0f};

    float h0s[16];
    #pragma unroll
    for (int op = 0; op < 8; ++op) {
        v2f acc = b0p[op];
        #pragma unroll
        for (int i = 0; i < 8; ++i) {
            const v2f fb = {feat[i], feat[i]};
            acc = FMA2(wt0[i * 8 + op], fb, acc);
        }
        if (grp == 1) acc = __builtin_elementwise_max(acc, zero);
        h0s[2 * op + 0] = acc[0];
        h0s[2 * op + 1] = acc[1];
    }

    float h1s[16];
    #pragma unroll
    for (int op = 0; op < 8; ++op) {
        v2f acc = b1p[op];
        #pragma unroll
        for (int i = 0; i < 16; ++i) {
            const v2f hb = {h0s[i], h0s[i]};
            acc = FMA2(wt1[i * 8 + op], hb, acc);
        }
        if (grp == 1) acc = __builtin_elementwise_max(acc, zero);
        h1s[2 * op + 0] = acc[0];
        h1s[2 * op + 1] = acc[1];
    }

    v2f acc2 = b2p[0];
    #pragma unroll
    for (int i = 0; i < 16; ++i) {
        const v2f hb = {h1s[i], h1s[i]};
        acc2 = FMA2(wt2[i], hb, acc2);
    }

    float2 o2;
    o2.x = acc2[0];
    o2.y = acc2[1];
    *reinterpret_cast<float2*>(out + 2 * gid) = o2;
}

extern "C" void kernel_launch(void* const* d_in, const int* in_sizes, int n_in,
                              void* d_out, int out_size, void* d_ws, size_t ws_size,
                              hipStream_t stream) {
    const float* x     = (const float*)d_in[0];
    const float* table = (const float*)d_in[1];
    const float* W0    = (const float*)d_in[2];
    const float* b0    = (const float*)d_in[3];
    const float* W1    = (const float*)d_in[4];
    const float* b1    = (const float*)d_in[5];
    const float* W2    = (const float*)d_in[6];
    const float* b2    = (const float*)d_in[7];
    const int*   group = (const int*)d_in[8];
    float* out = (float*)d_out;

    float2* dense  = (float2*)d_ws;           // [2440]  L0-2
    float2* dense3 = dense + NDENSE;          // [35937] L3
    const float* wt = (const float*)(dense + NTOTAL);   // 416 transposed floats
    const v2f* wt0 = (const v2f*)(wt);        // [8][8]  pairs
    const v2f* wt1 = (const v2f*)(wt + 128);  // [16][8] pairs
    const v2f* wt2 = (const v2f*)(wt + 384);  // [16][1] pairs

    const int n = in_sizes[0] / 3;   // 2097152
    dehash_kernel<<<(NTOTAL + NWT + 255) / 256, 256, 0, stream>>>(
        table, W0, W1, W2, dense);
    const int block = 256;
    const int grid = (n + block - 1) / block;
    ngp_fused<<<grid, block, 0, stream>>>(x, dense, dense3, wt0, wt1, wt2,
                                          b0, b1, b2, group, out, n);
}

// Round 16
// 132.787 us; speedup vs baseline: 1.3219x; 1.0123x over previous
//
#include <hip/hip_runtime.h>
#include <stdint.h>

// instant-NGP hash encode (L=4, F=2, T=19, res {2,5,12,32}) + MLP 8->16->16->2
// L0-2 densified (2440 entries) -> LDS direct-index. L3 densified 33^3 dense
// grid in d_ws. Packed fp32 (v_pk_fma_f32) interp + MLP with pre-transposed
// weights. NEW this round: 2 points/thread -> two independent dependency
// chains per thread (ILP), float2-vectorized x loads, float4 output store.

#define TBL_ENTRIES (1u << 19)
#define HASH_MASK   (TBL_ENTRIES - 1u)

#define D0 3
#define D1 6
#define D2 13
#define D3 33
#define N0 (D0*D0*D0)            // 27
#define N1 (D1*D1*D1)            // 216
#define N2 (D2*D2*D2)            // 2197
#define N3 (D3*D3*D3)            // 35937
#define NDENSE (N0 + N1 + N2)    // 2440 float2 (LDS)
#define NTOTAL (NDENSE + N3)     // 38377 float2 in d_ws
#define NWT    416               // 128 + 256 + 32 transposed weight floats

typedef float v2f __attribute__((ext_vector_type(2)));
#define FMA2(a,b,c) __builtin_elementwise_fma((a),(b),(c))

__global__ __launch_bounds__(256) void dehash_kernel(
    const float* __restrict__ table,
    const float* __restrict__ W0,   // [16,8]
    const float* __restrict__ W1,   // [16,16]
    const float* __restrict__ W2,   // [2,16]
    float2* __restrict__ dense)     // [NTOTAL] + wt[NWT] floats after
{
    const int i = blockIdx.x * 256 + threadIdx.x;
    if (i < NTOTAL) {
        int l, e, D;
        if (i < N0)           { l = 0; e = i;           D = D0; }
        else if (i < N0 + N1) { l = 1; e = i - N0;      D = D1; }
        else if (i < NDENSE)  { l = 2; e = i - N0 - N1; D = D2; }
        else                  { l = 3; e = i - NDENSE;  D = D3; }
        const int a = e / (D * D);
        const int r = e - a * D * D;
        const int b = r / D;
        const int c = r - b * D;
        const uint32_t h = ((uint32_t)a)
                         ^ (((uint32_t)b) * 2654435761u)
                         ^ (((uint32_t)c) * 805459861u);
        const float2* t2 = reinterpret_cast<const float2*>(table);
        dense[i] = t2[(size_t)l * TBL_ENTRIES + (h & HASH_MASK)];
    } else if (i < NTOTAL + NWT) {
        // transposed weights: wt0[i8][o16]=W0[o][i8]; wt1[i16][o16]=W1[o][i];
        // wt2[i16][o2]=W2[o][i]
        float* wt = reinterpret_cast<float*>(dense + NTOTAL);
        const int j = i - NTOTAL;
        float v;
        if (j < 128)      { const int ii = j >> 4, o = j & 15; v = W0[o * 8 + ii]; }
        else if (j < 384) { const int k = j - 128; const int ii = k >> 4, o = k & 15; v = W1[o * 16 + ii]; }
        else              { const int m = j - 384; const int ii = m >> 1, o = m & 1;  v = W2[o * 16 + ii]; }
        wt[j] = v;
    }
}

__global__ __launch_bounds__(256) void ngp_fused(
    const float* __restrict__ x,       // [N,3]
    const float2* __restrict__ dense,  // [2440] L0-2
    const float2* __restrict__ dense3, // [33][33][33] L3
    const v2f* __restrict__ wt0,       // [8][8]  pairs: {W0[2o][i],W0[2o+1][i]}
    const v2f* __restrict__ wt1,       // [16][8]
    const v2f* __restrict__ wt2,       // [16][1]
    const float* __restrict__ b0,      // [16]
    const float* __restrict__ b1,      // [16]
    const float* __restrict__ b2,      // [2]
    const int*   __restrict__ group,   // [1]
    float* __restrict__ out,           // [N,2]
    int n)
{
    __shared__ float2 sd[NDENSE];
    const int t = threadIdx.x;
    {   // coalesced stage: 2440 float2 = 1220 float4
        const float4* src4 = reinterpret_cast<const float4*>(dense);
        float4* dst4 = reinterpret_cast<float4*>(sd);
        #pragma unroll
        for (int i = 0; i < 5; ++i) {
            const int j = t + 256 * i;
            if (j < 1220) dst4[j] = src4[j];
        }
    }
    __syncthreads();

    const int pt0 = (blockIdx.x * 256 + t) * 2;   // two consecutive points
    if (pt0 + 1 >= n + 1) return;                  // n even; guard benign

    const int grp = *group;

    // ---- x loads: 24B contiguous as 3x float2
    const float2* xp = reinterpret_cast<const float2*>(x + 3 * pt0);
    const float2 xa = xp[0], xb = xp[1], xc = xp[2];
    float P[2][3];
    P[0][0] = (xa.x + 1.0f) * 0.5f;
    P[0][1] = (xa.y + 1.0f) * 0.5f;
    P[0][2] = (xb.x + 1.0f) * 0.5f;
    P[1][0] = (xb.y + 1.0f) * 0.5f;
    P[1][1] = (xc.x + 1.0f) * 0.5f;
    P[1][2] = (xc.y + 1.0f) * 0.5f;

    // ===== level 3 (res 32): dense [33][33][33], 8x16B loads issued FIRST
    float wcs3[2][8];
    v2f tv[2][8];
    #pragma unroll
    for (int p = 0; p < 2; ++p) {
        const float sx = P[p][0] * 32.0f, sy = P[p][1] * 32.0f, sz = P[p][2] * 32.0f;
        const float fx = floorf(sx), fy = floorf(sy), fz = floorf(sz);
        const float wx = sx - fx, wy = sy - fy, wz = sz - fz;
        const int ix = (int)fx, iy = (int)fy, iz = (int)fz;
        const float ux = 1.0f - wx, uy = 1.0f - wy, uz = 1.0f - wz;
        const float w00 = ux * uy, w10 = wx * uy, w01 = ux * wy, w11 = wx * wy;
        #pragma unroll
        for (int c = 0; c < 8; ++c) {
            const float wxy = (c & 2) ? ((c & 1) ? w11 : w01)
                                      : ((c & 1) ? w10 : w00);
            wcs3[p][c] = wxy * ((c & 4) ? wz : uz);
        }
        const float2* r00 = dense3 + (ix * D3 + iy) * D3 + iz;
        const float2* r10 = r00 + D3 * D3;
        const float2* r01 = r00 + D3;
        const float2* r11 = r10 + D3;
        tv[p][0] = *(const v2f*)&r00[0]; tv[p][4] = *(const v2f*)&r00[1];
        tv[p][1] = *(const v2f*)&r10[0]; tv[p][5] = *(const v2f*)&r10[1];
        tv[p][2] = *(const v2f*)&r01[0]; tv[p][6] = *(const v2f*)&r01[1];
        tv[p][3] = *(const v2f*)&r11[0]; tv[p][7] = *(const v2f*)&r11[1];
    }

    // ===== levels 0-2 from LDS (direct 3D index, packed accumulate)
    float feat[2][8];
    const float RESF[3] = {2.0f, 5.0f, 12.0f};
    const int   DIMS[3] = {D0, D1, D2};
    const int   BASE[3] = {0, N0, N0 + N1};
    #pragma unroll
    for (int p = 0; p < 2; ++p) {
        #pragma unroll
        for (int l = 0; l < 3; ++l) {
            const float res = RESF[l];
            const int   D   = DIMS[l];
            const float sx = P[p][0] * res, sy = P[p][1] * res, sz = P[p][2] * res;
            const float fx = floorf(sx), fy = floorf(sy), fz = floorf(sz);
            const float wx = sx - fx, wy = sy - fy, wz = sz - fz;
            const int ix = (int)fx, iy = (int)fy, iz = (int)fz;
            const int base = BASE[l] + (ix * D + iy) * D + iz;
            const float ux = 1.0f - wx, uy = 1.0f - wy, uz = 1.0f - wz;
            const float w00 = ux * uy, w10 = wx * uy, w01 = ux * wy, w11 = wx * wy;
            v2f acc = {0.0f, 0.0f};
            #pragma unroll
            for (int c = 0; c < 8; ++c) {
                const int o = base + ((c & 1) ? D * D : 0)
                                   + ((c & 2) ? D : 0)
                                   + ((c & 4) ? 1 : 0);
                const float wxy = (c & 2) ? ((c & 1) ? w11 : w01)
                                          : ((c & 1) ? w10 : w00);
                const float wc = wxy * ((c & 4) ? wz : uz);
                const v2f v = *(const v2f*)&sd[o];
                const v2f wb = {wc, wc};
                acc = FMA2(wb, v, acc);
            }
            feat[p][2 * l + 0] = acc[0];
            feat[p][2 * l + 1] = acc[1];
        }
    }

    // ===== combine level-3 (loads were in flight during LDS work)
    #pragma unroll
    for (int p = 0; p < 2; ++p) {
        v2f acc = {0.0f, 0.0f};
        #pragma unroll
        for (int c = 0; c < 8; ++c) {
            const v2f wb = {wcs3[p][c], wcs3[p][c]};
            acc = FMA2(wb, tv[p][c], acc);
        }
        feat[p][6] = acc[0];
        feat[p][7] = acc[1];
    }

    // ===== MLP, fully packed, both points interleaved by the scheduler
    const v2f* b0p = reinterpret_cast<const v2f*>(b0);   // [8]
    const v2f* b1p = reinterpret_cast<const v2f*>(b1);   // [8]
    const v2f* b2p = reinterpret_cast<const v2f*>(b2);   // [1]
    const v2f zero = {0.0f, 0.0f};

    float h0s[2][16];
    #pragma unroll
    for (int p = 0; p < 2; ++p) {
        #pragma unroll
        for (int op = 0; op < 8; ++op) {
            v2f acc = b0p[op];
            #pragma unroll
            for (int i = 0; i < 8; ++i) {
                const v2f fb = {feat[p][i], feat[p][i]};
                acc = FMA2(wt0[i * 8 + op], fb, acc);
            }
            if (grp == 1) acc = __builtin_elementwise_max(acc, zero);
            h0s[p][2 * op + 0] = acc[0];
            h0s[p][2 * op + 1] = acc[1];
        }
    }

    float h1s[2][16];
    #pragma unroll
    for (int p = 0; p < 2; ++p) {
        #pragma unroll
        for (int op = 0; op < 8; ++op) {
            v2f acc = b1p[op];
            #pragma unroll
            for (int i = 0; i < 16; ++i) {
                const v2f hb = {h0s[p][i], h0s[p][i]};
                acc = FMA2(wt1[i * 8 + op], hb, acc);
            }
            if (grp == 1) acc = __builtin_elementwise_max(acc, zero);
            h1s[p][2 * op + 0] = acc[0];
            h1s[p][2 * op + 1] = acc[1];
        }
    }

    v2f o0 = b2p[0], o1 = b2p[0];
    #pragma unroll
    for (int i = 0; i < 16; ++i) {
        const v2f hb0 = {h1s[0][i], h1s[0][i]};
        const v2f hb1 = {h1s[1][i], h1s[1][i]};
        o0 = FMA2(wt2[i], hb0, o0);
        o1 = FMA2(wt2[i], hb1, o1);
    }

    float4 ov;
    ov.x = o0[0]; ov.y = o0[1]; ov.z = o1[0]; ov.w = o1[1];
    *reinterpret_cast<float4*>(out + 2 * pt0) = ov;   // 16B aligned (pt0 even)
}

extern "C" void kernel_launch(void* const* d_in, const int* in_sizes, int n_in,
                              void* d_out, int out_size, void* d_ws, size_t ws_size,
                              hipStream_t stream) {
    const float* x     = (const float*)d_in[0];
    const float* table = (const float*)d_in[1];
    const float* W0    = (const float*)d_in[2];
    const float* b0    = (const float*)d_in[3];
    const float* W1    = (const float*)d_in[4];
    const float* b1    = (const float*)d_in[5];
    const float* W2    = (const float*)d_in[6];
    const float* b2    = (const float*)d_in[7];
    const int*   group = (const int*)d_in[8];
    float* out = (float*)d_out;

    float2* dense  = (float2*)d_ws;           // [2440]  L0-2
    float2* dense3 = dense + NDENSE;          // [35937] L3
    const float* wt = (const float*)(dense + NTOTAL);   // 416 transposed floats
    const v2f* wt0 = (const v2f*)(wt);        // [8][8]  pairs
    const v2f* wt1 = (const v2f*)(wt + 128);  // [16][8] pairs
    const v2f* wt2 = (const v2f*)(wt + 384);  // [16][1] pairs

    const int n = in_sizes[0] / 3;   // 2097152
    dehash_kernel<<<(NTOTAL + NWT + 255) / 256, 256, 0, stream>>>(
        table, W0, W1, W2, dense);
    const int block = 256;
    const int grid = (n / 2 + block - 1) / block;   // 2 points per thread
    ngp_fused<<<grid, block, 0, stream>>>(x, dense, dense3, wt0, wt1, wt2,
                                          b0, b1, b2, group, out, n);
}

// Round 18
// 132.739 us; speedup vs baseline: 1.3224x; 1.0004x over previous
//
#include <hip/hip_runtime.h>
#include <stdint.h>

// instant-NGP hash encode (L=4, F=2, T=19, res {2,5,12,32}) + MLP 8->16->16->2
// L0-2 densified (2440 entries) -> LDS direct-index. L3 densified 33^3 dense
// grid in d_ws. Packed fp32 interp + MLP, pre-transposed weights, 2 pts/thread.
// NEW this round: 512-thread blocks (same 19.5KB LDS/block) -> wave residency
// no longer capped by LDS-allocation granularity (4 blocks x 8 waves = 32).

#define TBL_ENTRIES (1u << 19)
#define HASH_MASK   (TBL_ENTRIES - 1u)

#define D0 3
#define D1 6
#define D2 13
#define D3 33
#define N0 (D0*D0*D0)            // 27
#define N1 (D1*D1*D1)            // 216
#define N2 (D2*D2*D2)            // 2197
#define N3 (D3*D3*D3)            // 35937
#define NDENSE (N0 + N1 + N2)    // 2440 float2 (LDS)
#define NTOTAL (NDENSE + N3)     // 38377 float2 in d_ws
#define NWT    416               // 128 + 256 + 32 transposed weight floats

typedef float v2f __attribute__((ext_vector_type(2)));
#define FMA2(a,b,c) __builtin_elementwise_fma((a),(b),(c))

__global__ __launch_bounds__(256) void dehash_kernel(
    const float* __restrict__ table,
    const float* __restrict__ W0,   // [16,8]
    const float* __restrict__ W1,   // [16,16]
    const float* __restrict__ W2,   // [2,16]
    float2* __restrict__ dense)     // [NTOTAL] + wt[NWT] floats after
{
    const int i = blockIdx.x * 256 + threadIdx.x;
    if (i < NTOTAL) {
        int l, e, D;
        if (i < N0)           { l = 0; e = i;           D = D0; }
        else if (i < N0 + N1) { l = 1; e = i - N0;      D = D1; }
        else if (i < NDENSE)  { l = 2; e = i - N0 - N1; D = D2; }
        else                  { l = 3; e = i - NDENSE;  D = D3; }
        const int a = e / (D * D);
        const int r = e - a * D * D;
        const int b = r / D;
        const int c = r - b * D;
        const uint32_t h = ((uint32_t)a)
                         ^ (((uint32_t)b) * 2654435761u)
                         ^ (((uint32_t)c) * 805459861u);
        const float2* t2 = reinterpret_cast<const float2*>(table);
        dense[i] = t2[(size_t)l * TBL_ENTRIES + (h & HASH_MASK)];
    } else if (i < NTOTAL + NWT) {
        // transposed weights: wt0[i8][o16]=W0[o][i8]; wt1[i16][o16]=W1[o][i];
        // wt2[i16][o2]=W2[o][i]
        float* wt = reinterpret_cast<float*>(dense + NTOTAL);
        const int j = i - NTOTAL;
        float v;
        if (j < 128)      { const int ii = j >> 4, o = j & 15; v = W0[o * 8 + ii]; }
        else if (j < 384) { const int k = j - 128; const int ii = k >> 4, o = k & 15; v = W1[o * 16 + ii]; }
        else              { const int m = j - 384; const int ii = m >> 1, o = m & 1;  v = W2[o * 16 + ii]; }
        wt[j] = v;
    }
}

__global__ __launch_bounds__(512) void ngp_fused(
    const float* __restrict__ x,       // [N,3]
    const float2* __restrict__ dense,  // [2440] L0-2
    const float2* __restrict__ dense3, // [33][33][33] L3
    const v2f* __restrict__ wt0,       // [8][8]  pairs: {W0[2o][i],W0[2o+1][i]}
    const v2f* __restrict__ wt1,       // [16][8]
    const v2f* __restrict__ wt2,       // [16][1]
    const float* __restrict__ b0,      // [16]
    const float* __restrict__ b1,      // [16]
    const float* __restrict__ b2,      // [2]
    const int*   __restrict__ group,   // [1]
    float* __restrict__ out,           // [N,2]
    int n)
{
    __shared__ float2 sd[NDENSE];
    const int t = threadIdx.x;
    {   // coalesced stage: 2440 float2 = 1220 float4, 512 threads x 3 iters
        const float4* src4 = reinterpret_cast<const float4*>(dense);
        float4* dst4 = reinterpret_cast<float4*>(sd);
        #pragma unroll
        for (int i = 0; i < 3; ++i) {
            const int j = t + 512 * i;
            if (j < 1220) dst4[j] = src4[j];
        }
    }
    __syncthreads();

    const int pt0 = (blockIdx.x * 512 + t) * 2;   // two consecutive points
    if (pt0 >= n) return;

    const int grp = *group;

    // ---- x loads: 24B contiguous as 3x float2
    const float2* xp = reinterpret_cast<const float2*>(x + 3 * pt0);
    const float2 xa = xp[0], xb = xp[1], xc = xp[2];
    float P[2][3];
    P[0][0] = (xa.x + 1.0f) * 0.5f;
    P[0][1] = (xa.y + 1.0f) * 0.5f;
    P[0][2] = (xb.x + 1.0f) * 0.5f;
    P[1][0] = (xb.y + 1.0f) * 0.5f;
    P[1][1] = (xc.x + 1.0f) * 0.5f;
    P[1][2] = (xc.y + 1.0f) * 0.5f;

    // ===== level 3 (res 32): dense [33][33][33], 8x16B loads issued FIRST
    float wcs3[2][8];
    v2f tv[2][8];
    #pragma unroll
    for (int p = 0; p < 2; ++p) {
        const float sx = P[p][0] * 32.0f, sy = P[p][1] * 32.0f, sz = P[p][2] * 32.0f;
        const float fx = floorf(sx), fy = floorf(sy), fz = floorf(sz);
        const float wx = sx - fx, wy = sy - fy, wz = sz - fz;
        const int ix = (int)fx, iy = (int)fy, iz = (int)fz;
        const float ux = 1.0f - wx, uy = 1.0f - wy, uz = 1.0f - wz;
        const float w00 = ux * uy, w10 = wx * uy, w01 = ux * wy, w11 = wx * wy;
        #pragma unroll
        for (int c = 0; c < 8; ++c) {
            const float wxy = (c & 2) ? ((c & 1) ? w11 : w01)
                                      : ((c & 1) ? w10 : w00);
            wcs3[p][c] = wxy * ((c & 4) ? wz : uz);
        }
        const float2* r00 = dense3 + (ix * D3 + iy) * D3 + iz;
        const float2* r10 = r00 + D3 * D3;
        const float2* r01 = r00 + D3;
        const float2* r11 = r10 + D3;
        tv[p][0] = *(const v2f*)&r00[0]; tv[p][4] = *(const v2f*)&r00[1];
        tv[p][1] = *(const v2f*)&r10[0]; tv[p][5] = *(const v2f*)&r10[1];
        tv[p][2] = *(const v2f*)&r01[0]; tv[p][6] = *(const v2f*)&r01[1];
        tv[p][3] = *(const v2f*)&r11[0]; tv[p][7] = *(const v2f*)&r11[1];
    }

    // ===== levels 0-2 from LDS (direct 3D index, packed accumulate)
    float feat[2][8];
    const float RESF[3] = {2.0f, 5.0f, 12.0f};
    const int   DIMS[3] = {D0, D1, D2};
    const int   BASE[3] = {0, N0, N0 + N1};
    #pragma unroll
    for (int p = 0; p < 2; ++p) {
        #pragma unroll
        for (int l = 0; l < 3; ++l) {
            const float res = RESF[l];
            const int   D   = DIMS[l];
            const float sx = P[p][0] * res, sy = P[p][1] * res, sz = P[p][2] * res;
            const float fx = floorf(sx), fy = floorf(sy), fz = floorf(sz);
            const float wx = sx - fx, wy = sy - fy, wz = sz - fz;
            const int ix = (int)fx, iy = (int)fy, iz = (int)fz;
            const int base = BASE[l] + (ix * D + iy) * D + iz;
            const float ux = 1.0f - wx, uy = 1.0f - wy, uz = 1.0f - wz;
            const float w00 = ux * uy, w10 = wx * uy, w01 = ux * wy, w11 = wx * wy;
            v2f acc = {0.0f, 0.0f};
            #pragma unroll
            for (int c = 0; c < 8; ++c) {
                const int o = base + ((c & 1) ? D * D : 0)
                                   + ((c & 2) ? D : 0)
                                   + ((c & 4) ? 1 : 0);
                const float wxy = (c & 2) ? ((c & 1) ? w11 : w01)
                                          : ((c & 1) ? w10 : w00);
                const float wc = wxy * ((c & 4) ? wz : uz);
                const v2f v = *(const v2f*)&sd[o];
                const v2f wb = {wc, wc};
                acc = FMA2(wb, v, acc);
            }
            feat[p][2 * l + 0] = acc[0];
            feat[p][2 * l + 1] = acc[1];
        }
    }

    // ===== combine level-3 (loads were in flight during LDS work)
    #pragma unroll
    for (int p = 0; p < 2; ++p) {
        v2f acc = {0.0f, 0.0f};
        #pragma unroll
        for (int c = 0; c < 8; ++c) {
            const v2f wb = {wcs3[p][c], wcs3[p][c]};
            acc = FMA2(wb, tv[p][c], acc);
        }
        feat[p][6] = acc[0];
        feat[p][7] = acc[1];
    }

    // ===== MLP, fully packed, both points interleaved by the scheduler
    const v2f* b0p = reinterpret_cast<const v2f*>(b0);   // [8]
    const v2f* b1p = reinterpret_cast<const v2f*>(b1);   // [8]
    const v2f* b2p = reinterpret_cast<const v2f*>(b2);   // [1]
    const v2f zero = {0.0f, 0.0f};

    float h0s[2][16];
    #pragma unroll
    for (int p = 0; p < 2; ++p) {
        #pragma unroll
        for (int op = 0; op < 8; ++op) {
            v2f acc = b0p[op];
            #pragma unroll
            for (int i = 0; i < 8; ++i) {
                const v2f fb = {feat[p][i], feat[p][i]};
                acc = FMA2(wt0[i * 8 + op], fb, acc);
            }
            if (grp == 1) acc = __builtin_elementwise_max(acc, zero);
            h0s[p][2 * op + 0] = acc[0];
            h0s[p][2 * op + 1] = acc[1];
        }
    }

    float h1s[2][16];
    #pragma unroll
    for (int p = 0; p < 2; ++p) {
        #pragma unroll
        for (int op = 0; op < 8; ++op) {
            v2f acc = b1p[op];
            #pragma unroll
            for (int i = 0; i < 16; ++i) {
                const v2f hb = {h0s[p][i], h0s[p][i]};
                acc = FMA2(wt1[i * 8 + op], hb, acc);
            }
            if (grp == 1) acc = __builtin_elementwise_max(acc, zero);
            h1s[p][2 * op + 0] = acc[0];
            h1s[p][2 * op + 1] = acc[1];
        }
    }

    v2f o0 = b2p[0], o1 = b2p[0];
    #pragma unroll
    for (int i = 0; i < 16; ++i) {
        const v2f hb0 = {h1s[0][i], h1s[0][i]};
        const v2f hb1 = {h1s[1][i], h1s[1][i]};
        o0 = FMA2(wt2[i], hb0, o0);
        o1 = FMA2(wt2[i], hb1, o1);
    }

    float4 ov;
    ov.x = o0[0]; ov.y = o0[1]; ov.z = o1[0]; ov.w = o1[1];
    *reinterpret_cast<float4*>(out + 2 * pt0) = ov;   // 16B aligned (pt0 even)
}

extern "C" void kernel_launch(void* const* d_in, const int* in_sizes, int n_in,
                              void* d_out, int out_size, void* d_ws, size_t ws_size,
                              hipStream_t stream) {
    const float* x     = (const float*)d_in[0];
    const float* table = (const float*)d_in[1];
    const float* W0    = (const float*)d_in[2];
    const float* b0    = (const float*)d_in[3];
    const float* W1    = (const float*)d_in[4];
    const float* b1    = (const float*)d_in[5];
    const float* W2    = (const float*)d_in[6];
    const float* b2    = (const float*)d_in[7];
    const int*   group = (const int*)d_in[8];
    float* out = (float*)d_out;

    float2* dense  = (float2*)d_ws;           // [2440]  L0-2
    float2* dense3 = dense + NDENSE;          // [35937] L3
    const float* wt = (const float*)(dense + NTOTAL);   // 416 transposed floats
    const v2f* wt0 = (const v2f*)(wt);        // [8][8]  pairs
    const v2f* wt1 = (const v2f*)(wt + 128);  // [16][8] pairs
    const v2f* wt2 = (const v2f*)(wt + 384);  // [16][1] pairs

    const int n = in_sizes[0] / 3;   // 2097152
    dehash_kernel<<<(NTOTAL + NWT + 255) / 256, 256, 0, stream>>>(
        table, W0, W1, W2, dense);
    const int block = 512;
    const int grid = (n / 2 + block - 1) / block;   // 2 points per thread
    ngp_fused<<<grid, block, 0, stream>>>(x, dense, dense3, wt0, wt1, wt2,
                                          b0, b1, b2, group, out, n);
}